// Round 6
// baseline (240.021 us; speedup 1.0000x reference)
//
#include <hip/hip_runtime.h>
#include <hip/hip_bf16.h>
#include <hip/hip_fp16.h>
#include <hip/hip_cooperative_groups.h>

namespace cg = cooperative_groups;

#define N_PIX (512 * 512)   // 262144 pixels
#define N_CLU 4096
#define N_ROW 256           // 32*8 batch rows
#define CHUNK 1024
#define NCHUNK (N_PIX / CHUNK)  // 256

typedef unsigned int u32;
typedef unsigned short u16;
typedef float f32x4 __attribute__((ext_vector_type(4)));

// ===========================================================================
// Fused deterministic counting sort (one cooperative kernel, 256x256).
// P1 hist -> P2 per-cluster chunk-scan + counts -> P3 base scan -> P4 stable
// scatter producing rank[p].
// ===========================================================================
__global__ __launch_bounds__(256) void k_sort_fused(
    const int* __restrict__ map, int* __restrict__ hist,
    int* __restrict__ base, int* __restrict__ counts, int* __restrict__ rank) {
  cg::grid_group grid = cg::this_grid();
  __shared__ int sm[N_CLU];  // reused: bins / scan part / cursors
  const int bid = blockIdx.x;
  const int t = threadIdx.x;

  // ---- P1: per-chunk histogram (chunk = bid, 1024 px) ----
  for (int i = t; i < N_CLU; i += 256) sm[i] = 0;
  __syncthreads();
  {
    const int4 m4 = reinterpret_cast<const int4*>(map)[bid * 256 + t];
    atomicAdd(&sm[m4.x], 1);
    atomicAdd(&sm[m4.y], 1);
    atomicAdd(&sm[m4.z], 1);
    atomicAdd(&sm[m4.w], 1);
  }
  __syncthreads();
  for (int i = t; i < N_CLU; i += 256) hist[bid * N_CLU + i] = sm[i];
  grid.sync();

  // ---- P2: exclusive scan over the 256 chunks, per cluster ----
  // block owns clusters bid*16..+15; thread (cl = t&15, seg = t>>4) scans
  // chunks [seg*16, seg*16+16).
  {
    const int cl = t & 15;
    const int seg = t >> 4;
    const int c = bid * 16 + cl;
    int s = 0;
#pragma unroll 4
    for (int ch = seg * 16; ch < seg * 16 + 16; ++ch) s += hist[ch * N_CLU + c];
    int* part = sm;  // [16][17]
    part[cl * 17 + seg] = s;
    __syncthreads();
    int excl = 0;
    for (int j = 0; j < seg; ++j) excl += part[cl * 17 + j];
    if (seg == 15) counts[c] = excl + s;
    int run = excl;
#pragma unroll 4
    for (int ch = seg * 16; ch < seg * 16 + 16; ++ch) {
      int v = hist[ch * N_CLU + c];
      hist[ch * N_CLU + c] = run;
      run += v;
    }
  }
  grid.sync();

  // ---- P3: exclusive scan counts[4096] -> base[4096] (block 0 only) ----
  if (bid == 0) {
    int loc[16];
    int s = 0;
#pragma unroll
    for (int j = 0; j < 16; ++j) {
      loc[j] = s;
      s += counts[t * 16 + j];
    }
    sm[t] = s;
    __syncthreads();
    if (t == 0) {
      int r = 0;
      for (int i = 0; i < 256; ++i) {
        int v = sm[i];
        sm[i] = r;
        r += v;
      }
    }
    __syncthreads();
    const int b = sm[t];
#pragma unroll
    for (int j = 0; j < 16; ++j) base[t * 16 + j] = b + loc[j];
  }
  grid.sync();

  // ---- P4: stable scatter -> rank[p] (chunk = bid; wave 0 does groups) ----
  for (int i = t; i < N_CLU; i += 256) sm[i] = base[i] + hist[bid * N_CLU + i];
  __syncthreads();
  if (t < 64) {
    const int lane = t;
    for (int g = 0; g < CHUNK / 64; ++g) {
      const int p = bid * CHUNK + g * 64 + lane;
      const int c = map[p];
      int r = 0, cnt = 0;
#pragma unroll 64
      for (int k = 0; k < 64; ++k) {
        const int ck = __shfl(c, k, 64);
        cnt += (ck == c) ? 1 : 0;
        r += ((ck == c) && (k < lane)) ? 1 : 0;
      }
      const int pos = sm[c] + r;
      rank[p] = pos;
      // single-wave: program order makes the cursor bump safe, no barrier
      if (r == cnt - 1) sm[c] = pos + 1;
    }
  }
}

// ===========================================================================
// K4: sorted transpose to fp16. sortedT[rank[p]] = fp16(data[:, p]) as a
// contiguous 512B row-vector (256 rows x 2B). Tile: 64 px x 256 rows.
// ===========================================================================
__global__ __launch_bounds__(512) void k_transpose_sorted(
    const float* __restrict__ data, const int* __restrict__ rank,
    uint4* __restrict__ sortedT) {
  __shared__ u16 tile[64][258];  // row stride 516B -> bank stride 1
  __shared__ int rk_s[64];
  const int p0 = blockIdx.x * 64;
  const int t = threadIdx.x;

  if (t < 64) rk_s[t] = rank[p0 + t];

  const int lane4 = t & 15;  // which float4 of the 64-px row segment
  const int rowA = t >> 4;   // 0..31
  const f32x4* d4 = reinterpret_cast<const f32x4*>(data);
#pragma unroll
  for (int k = 0; k < 8; ++k) {
    const int row = rowA + k * 32;
    const f32x4 v = __builtin_nontemporal_load(
        d4 + (size_t)row * (N_PIX / 4) + (p0 >> 2) + lane4);
    const int px = lane4 * 4;
    tile[px + 0][row] = __half_as_ushort(__float2half(v.x));
    tile[px + 1][row] = __half_as_ushort(__float2half(v.y));
    tile[px + 2][row] = __half_as_ushort(__float2half(v.z));
    tile[px + 3][row] = __half_as_ushort(__float2half(v.w));
  }
  __syncthreads();

  const int chunk = t & 31;  // 16B chunk (8 rows) of the vector
  const int pxs = t >> 5;    // 0..15
#pragma unroll
  for (int it = 0; it < 4; ++it) {
    const int px2 = pxs + 16 * it;
    const int rk = rk_s[px2];
    const u32* src = reinterpret_cast<const u32*>(&tile[px2][chunk * 8]);
    uint4 v;
    v.x = src[0];
    v.y = src[1];
    v.z = src[2];
    v.w = src[3];
    sortedT[(size_t)rk * 32 + chunk] = v;
  }
}

// ===========================================================================
// K5: reduce. Block per cluster (XCD-swizzled); stream contiguous 512B
// pixel-vectors, 2x-unrolled, fp32 register accumulate, LDS tree.
// ===========================================================================
__global__ __launch_bounds__(256) void k_reduce(const uint4* __restrict__ sortedT,
                                                const int* __restrict__ base,
                                                const int* __restrict__ counts,
                                                float* __restrict__ out) {
  __shared__ float red[8][256];
  const int bid = blockIdx.x;
  const int c = ((bid & 7) << 9) | (bid >> 3);  // 4096 = 8 XCDs x 512
  const int t = threadIdx.x;
  const int chunk = t & 31;  // rows chunk*8 .. chunk*8+7
  const int g = t >> 5;      // 0..7 pixel interleave
  const int bs = base[c];
  const int cnt = counts[c];
  float acc[8] = {0.f, 0.f, 0.f, 0.f, 0.f, 0.f, 0.f, 0.f};

  const uint4* p = sortedT + (size_t)bs * 32 + chunk;
  int i = g;
  for (; i + 8 < cnt; i += 16) {
    const uint4 va = p[(size_t)i * 32];
    const uint4 vb = p[(size_t)(i + 8) * 32];
#pragma unroll
    for (int j = 0; j < 4; ++j) {
      const u32 wa = (&va.x)[j];
      const u32 wb = (&vb.x)[j];
      const float2 fa = __half22float2(*reinterpret_cast<const __half2*>(&wa));
      const float2 fb = __half22float2(*reinterpret_cast<const __half2*>(&wb));
      acc[2 * j + 0] += fa.x + fb.x;
      acc[2 * j + 1] += fa.y + fb.y;
    }
  }
  for (; i < cnt; i += 8) {
    const uint4 va = p[(size_t)i * 32];
#pragma unroll
    for (int j = 0; j < 4; ++j) {
      const u32 wa = (&va.x)[j];
      const float2 fa = __half22float2(*reinterpret_cast<const __half2*>(&wa));
      acc[2 * j + 0] += fa.x;
      acc[2 * j + 1] += fa.y;
    }
  }

#pragma unroll
  for (int j = 0; j < 8; ++j) red[g][chunk * 8 + j] = acc[j];
  __syncthreads();
  const float inv = cnt ? 1.0f / (float)cnt : 0.0f;
  float s = 0.f;
#pragma unroll
  for (int j = 0; j < 8; ++j) s += red[j][t];
  out[(size_t)t * N_CLU + c] = s * inv;  // row = t
}

// ===========================================================================
// Tier-3 fallback (tiny ws): LDS-atomic version.
// ===========================================================================
__global__ __launch_bounds__(256) void count_kernel(const int* __restrict__ mapping,
                                                    int* __restrict__ counts) {
  __shared__ int bins[N_CLU];
  for (int i = threadIdx.x; i < N_CLU; i += 256) bins[i] = 0;
  __syncthreads();
  const int stride = gridDim.x * 256;
  for (int i = blockIdx.x * 256 + threadIdx.x; i < N_PIX; i += stride)
    atomicAdd(&bins[mapping[i]], 1);
  __syncthreads();
  for (int i = threadIdx.x; i < N_CLU; i += 256) {
    int v = bins[i];
    if (v) atomicAdd(&counts[i], v);
  }
}

__global__ __launch_bounds__(1024) void mean_kernel(
    const float* __restrict__ data, const int* __restrict__ mapping,
    const int* __restrict__ counts, float* __restrict__ out) {
  __shared__ float bins[N_CLU];
  const int b = blockIdx.x;
  for (int i = threadIdx.x; i < N_CLU; i += 1024) bins[i] = 0.0f;
  __syncthreads();
  const float4* drow = reinterpret_cast<const float4*>(data + (size_t)b * N_PIX);
  const int4* map4 = reinterpret_cast<const int4*>(mapping);
  for (int i = threadIdx.x; i < N_PIX / 4; i += 1024) {
    float4 v = drow[i];
    int4 m = map4[i];
    __hip_atomic_fetch_add(&bins[m.x], v.x, __ATOMIC_RELAXED, __HIP_MEMORY_SCOPE_WORKGROUP);
    __hip_atomic_fetch_add(&bins[m.y], v.y, __ATOMIC_RELAXED, __HIP_MEMORY_SCOPE_WORKGROUP);
    __hip_atomic_fetch_add(&bins[m.z], v.z, __ATOMIC_RELAXED, __HIP_MEMORY_SCOPE_WORKGROUP);
    __hip_atomic_fetch_add(&bins[m.w], v.w, __ATOMIC_RELAXED, __HIP_MEMORY_SCOPE_WORKGROUP);
  }
  __syncthreads();
  float* orow = out + (size_t)b * N_CLU;
  for (int c = threadIdx.x; c < N_CLU; c += 1024)
    orow[c] = bins[c] / (float)counts[c];
}

// ===========================================================================
extern "C" void kernel_launch(void* const* d_in, const int* in_sizes, int n_in,
                              void* d_out, int out_size, void* d_ws, size_t ws_size,
                              hipStream_t stream) {
  const float* data = (const float*)d_in[0];   // [256][262144] fp32
  const int* mapping = (const int*)d_in[1];    // [262144] int32
  float* out = (float*)d_out;                  // [256][4096] fp32
  char* ws = (char*)d_ws;

  const size_t OFF_HIST = 0;
  const size_t OFF_BASE = (size_t)NCHUNK * N_CLU * 4;          // 4 MiB
  const size_t OFF_CNT = OFF_BASE + (size_t)N_CLU * 4;
  const size_t OFF_RANK = OFF_CNT + (size_t)N_CLU * 4;
  const size_t OFF_SORT = OFF_RANK + (size_t)N_PIX * 4;        // 16B-aligned
  const size_t NEED = OFF_SORT + (size_t)N_PIX * N_ROW * 2;    // ~133 MiB

  if (ws_size >= NEED) {
    int* hist = (int*)(ws + OFF_HIST);
    int* base = (int*)(ws + OFF_BASE);
    int* counts = (int*)(ws + OFF_CNT);
    int* rank = (int*)(ws + OFF_RANK);
    uint4* sortedT = (uint4*)(ws + OFF_SORT);

    void* kargs[] = {(void*)&mapping, (void*)&hist, (void*)&base,
                     (void*)&counts, (void*)&rank};
    (void)hipLaunchCooperativeKernel((void*)k_sort_fused, dim3(NCHUNK),
                                     dim3(256), kargs, 0, stream);
    k_transpose_sorted<<<N_PIX / 64, 512, 0, stream>>>(data, rank, sortedT);
    k_reduce<<<N_CLU, 256, 0, stream>>>(sortedT, base, counts, out);
  } else {
    int* counts = (int*)ws;
    (void)hipMemsetAsync(counts, 0, N_CLU * sizeof(int), stream);
    count_kernel<<<256, 256, 0, stream>>>(mapping, counts);
    mean_kernel<<<N_ROW, 1024, 0, stream>>>(data, mapping, counts, out);
  }
}

// Round 7
// 145.173 us; speedup vs baseline: 1.6533x; 1.6533x over previous
//
#include <hip/hip_runtime.h>
#include <hip/hip_bf16.h>
#include <hip/hip_fp16.h>

#define N_PIX (512 * 512)   // 262144 pixels
#define N_CLU 4096
#define N_ROW 256           // 32*8 batch rows
#define CHUNK 1024
#define NCHUNK (N_PIX / CHUNK)  // 256

typedef unsigned int u32;
typedef unsigned short u16;
typedef float f32x4 __attribute__((ext_vector_type(4)));

// ===========================================================================
// Deterministic counting sort of pixels by cluster -> perm/base/counts.
// (4 small kernels; cooperative fusion measured +110us regression in R6.)
// ===========================================================================

// K1: per-chunk histogram. hist[ch][c] = #pixels of cluster c in chunk ch.
__global__ __launch_bounds__(256) void k_hist(const int* __restrict__ map,
                                              int* __restrict__ hist) {
  __shared__ int h[N_CLU];
  for (int i = threadIdx.x; i < N_CLU; i += 256) h[i] = 0;
  __syncthreads();
  const int4 m4 =
      reinterpret_cast<const int4*>(map)[blockIdx.x * 256 + threadIdx.x];
  atomicAdd(&h[m4.x], 1);
  atomicAdd(&h[m4.y], 1);
  atomicAdd(&h[m4.z], 1);
  atomicAdd(&h[m4.w], 1);
  __syncthreads();
  int* o = hist + blockIdx.x * N_CLU;
  for (int i = threadIdx.x; i < N_CLU; i += 256) o[i] = h[i];
}

// K2: in-place exclusive scan of hist over the chunk axis, per cluster.
__global__ __launch_bounds__(256) void k_scan_chunks(int* __restrict__ hist,
                                                     int* __restrict__ counts) {
  __shared__ int qsum[4][64];
  const int cl = threadIdx.x & 63;
  const int q = threadIdx.x >> 6;            // 0..3, chunks [q*64, q*64+64)
  const int c = blockIdx.x * 64 + cl;
  int s = 0;
#pragma unroll 8
  for (int ch = q * 64; ch < q * 64 + 64; ++ch) s += hist[ch * N_CLU + c];
  qsum[q][cl] = s;
  __syncthreads();
  int qb = 0;
  for (int j = 0; j < 4; ++j) qb += (j < q) ? qsum[j][cl] : 0;
  if (q == 3) counts[c] = qb + s;
  int run = qb;
#pragma unroll 4
  for (int ch = q * 64; ch < q * 64 + 64; ++ch) {
    int v = hist[ch * N_CLU + c];
    hist[ch * N_CLU + c] = run;
    run += v;
  }
}

// K2b: exclusive scan of counts[4096] -> base[4096]. Single block.
__global__ __launch_bounds__(256) void k_scan_base(const int* __restrict__ counts,
                                                   int* __restrict__ base) {
  __shared__ int part[256];
  const int t = threadIdx.x;
  int loc[16];
  int s = 0;
#pragma unroll
  for (int j = 0; j < 16; ++j) {
    loc[j] = s;
    s += counts[t * 16 + j];
  }
  part[t] = s;
  __syncthreads();
  if (t == 0) {
    int r = 0;
    for (int i = 0; i < 256; ++i) {
      int v = part[i];
      part[i] = r;
      r += v;
    }
  }
  __syncthreads();
  const int b = part[t];
#pragma unroll
  for (int j = 0; j < 16; ++j) base[t * 16 + j] = b + loc[j];
}

// K3: stable scatter -> perm[pos] = pixel id (rank array no longer needed).
__global__ __launch_bounds__(64) void k_scatter(const int* __restrict__ map,
                                                const int* __restrict__ hist,
                                                const int* __restrict__ base,
                                                int* __restrict__ perm) {
  __shared__ int off[N_CLU];
  const int ch = blockIdx.x;
  const int lane = threadIdx.x;
  for (int i = lane; i < N_CLU; i += 64) off[i] = base[i] + hist[ch * N_CLU + i];
  __syncthreads();
  for (int g = 0; g < CHUNK / 64; ++g) {
    const int p = ch * CHUNK + g * 64 + lane;
    const int c = map[p];
    int r = 0, cnt = 0;
    for (int k = 0; k < 64; ++k) {
      const int ck = __shfl(c, k, 64);
      cnt += (ck == c) ? 1 : 0;
      r += ((ck == c) && (k < lane)) ? 1 : 0;
    }
    const int pos = off[c] + r;
    perm[pos] = p;
    __syncthreads();
    if (r == cnt - 1) off[c] = pos + 1;  // last occurrence bumps the cursor
    __syncthreads();
  }
}

// ===========================================================================
// K4: PIXEL-ORDER transpose to fp16. transT[p] = fp16(data[:, p]) as a
// contiguous 512B vector. No rank: writes are perfectly sequential
// (64 KiB contiguous per block); the sort permutation moves to the reduce's
// read side (L3-resident gathers).
// 128px tile: 512B-granular strip reads. Dynamic LDS 66 KiB (2 blocks/CU).
// ===========================================================================
__global__ __launch_bounds__(512) void k_transpose128(
    const float* __restrict__ data, uint4* __restrict__ transT) {
  extern __shared__ u16 tile[];  // [128][258]; pad 2 -> stage A <=4-way
  const int p0 = blockIdx.x * 128;
  const int t = threadIdx.x;

  // Stage A: per row, 32 lanes x 16B = 512B contiguous strip; 16 rows/pass.
  const int lane4 = t & 31;
  const int rowA = t >> 5;  // 0..15
  const f32x4* d4 = reinterpret_cast<const f32x4*>(data);
#pragma unroll
  for (int k = 0; k < 16; ++k) {
    const int row = rowA + k * 16;
    const f32x4 v = __builtin_nontemporal_load(
        d4 + (size_t)row * (N_PIX / 4) + (p0 >> 2) + lane4);
    const int px = lane4 * 4;
    tile[(px + 0) * 258 + row] = __half_as_ushort(__float2half(v.x));
    tile[(px + 1) * 258 + row] = __half_as_ushort(__float2half(v.y));
    tile[(px + 2) * 258 + row] = __half_as_ushort(__float2half(v.z));
    tile[(px + 3) * 258 + row] = __half_as_ushort(__float2half(v.w));
  }
  __syncthreads();

  // Stage B: per pixel, one contiguous 512B write (32 lanes x 16B);
  // wave walks a contiguous 8-px (4 KiB) region.
  const int chunk = t & 31;  // 16B chunk (8 rows) of the vector
  const int pxs = t >> 5;    // 0..15
#pragma unroll
  for (int it = 0; it < 8; ++it) {
    const int px2 = pxs * 8 + it;
    const u32* src = reinterpret_cast<const u32*>(&tile[px2 * 258 + chunk * 8]);
    uint4 v;
    v.x = src[0];
    v.y = src[1];
    v.z = src[2];
    v.w = src[3];
    transT[(size_t)(p0 + px2) * 32 + chunk] = v;
  }
}

// Fallback: 64px tile, static LDS (33 KiB), if >64KiB dynamic LDS refused.
__global__ __launch_bounds__(512) void k_transpose64(
    const float* __restrict__ data, uint4* __restrict__ transT) {
  __shared__ u16 tile[64][258];
  const int p0 = blockIdx.x * 64;
  const int t = threadIdx.x;
  const int lane4 = t & 15;
  const int rowA = t >> 4;  // 0..31
  const f32x4* d4 = reinterpret_cast<const f32x4*>(data);
#pragma unroll
  for (int k = 0; k < 8; ++k) {
    const int row = rowA + k * 32;
    const f32x4 v = __builtin_nontemporal_load(
        d4 + (size_t)row * (N_PIX / 4) + (p0 >> 2) + lane4);
    const int px = lane4 * 4;
    tile[px + 0][row] = __half_as_ushort(__float2half(v.x));
    tile[px + 1][row] = __half_as_ushort(__float2half(v.y));
    tile[px + 2][row] = __half_as_ushort(__float2half(v.z));
    tile[px + 3][row] = __half_as_ushort(__float2half(v.w));
  }
  __syncthreads();
  const int chunk = t & 31;
  const int pxs = t >> 5;  // 0..15
#pragma unroll
  for (int it = 0; it < 4; ++it) {
    const int px2 = pxs * 4 + it;
    const u32* src = reinterpret_cast<const u32*>(&tile[px2][chunk * 8]);
    uint4 v;
    v.x = src[0];
    v.y = src[1];
    v.z = src[2];
    v.w = src[3];
    transT[(size_t)(p0 + px2) * 32 + chunk] = v;
  }
}

// ===========================================================================
// K5: gather-reduce. Block per cluster (XCD-swizzled). perm slice staged in
// LDS, then random 512B pixel-vector reads (L3-resident), fp32 register
// accumulate, 2-deep unroll, LDS tree, single-writer output.
// ===========================================================================
__global__ __launch_bounds__(256) void k_reduce_g(
    const uint4* __restrict__ transT, const int* __restrict__ perm,
    const int* __restrict__ base, const int* __restrict__ counts,
    float* __restrict__ out) {
  __shared__ int perm_s[1024];
  __shared__ float red[8][256];
  const int bid = blockIdx.x;
  const int c = ((bid & 7) << 9) | (bid >> 3);  // 4096 = 8 XCDs x 512
  const int t = threadIdx.x;
  const int chunk = t & 31;  // rows chunk*8 .. chunk*8+7
  const int g = t >> 5;      // 0..7 pixel interleave
  const int bs = base[c];
  const int cnt = counts[c];
  float acc[8] = {0.f, 0.f, 0.f, 0.f, 0.f, 0.f, 0.f, 0.f};

  for (int start = 0; start < cnt; start += 1024) {
    const int n = min(1024, cnt - start);
    __syncthreads();
    for (int i = t; i < n; i += 256) perm_s[i] = perm[bs + start + i];
    __syncthreads();
    int i = g;
    for (; i + 8 < n; i += 16) {
      const int pa = perm_s[i];
      const int pb = perm_s[i + 8];
      const uint4 va = transT[(size_t)pa * 32 + chunk];
      const uint4 vb = transT[(size_t)pb * 32 + chunk];
#pragma unroll
      for (int j = 0; j < 4; ++j) {
        const u32 wa = (&va.x)[j];
        const u32 wb = (&vb.x)[j];
        const float2 fa = __half22float2(*reinterpret_cast<const __half2*>(&wa));
        const float2 fb = __half22float2(*reinterpret_cast<const __half2*>(&wb));
        acc[2 * j + 0] += fa.x + fb.x;
        acc[2 * j + 1] += fa.y + fb.y;
      }
    }
    for (; i < n; i += 8) {
      const int pa = perm_s[i];
      const uint4 va = transT[(size_t)pa * 32 + chunk];
#pragma unroll
      for (int j = 0; j < 4; ++j) {
        const u32 wa = (&va.x)[j];
        const float2 fa = __half22float2(*reinterpret_cast<const __half2*>(&wa));
        acc[2 * j + 0] += fa.x;
        acc[2 * j + 1] += fa.y;
      }
    }
  }

#pragma unroll
  for (int j = 0; j < 8; ++j) red[g][chunk * 8 + j] = acc[j];
  __syncthreads();
  const float inv = cnt ? 1.0f / (float)cnt : 0.0f;
  float s = 0.f;
#pragma unroll
  for (int j = 0; j < 8; ++j) s += red[j][t];
  out[(size_t)t * N_CLU + c] = s * inv;  // row = t
}

// ===========================================================================
// Tier-3 fallback (tiny ws): LDS-atomic version.
// ===========================================================================
__global__ __launch_bounds__(256) void count_kernel(const int* __restrict__ mapping,
                                                    int* __restrict__ counts) {
  __shared__ int bins[N_CLU];
  for (int i = threadIdx.x; i < N_CLU; i += 256) bins[i] = 0;
  __syncthreads();
  const int stride = gridDim.x * 256;
  for (int i = blockIdx.x * 256 + threadIdx.x; i < N_PIX; i += stride)
    atomicAdd(&bins[mapping[i]], 1);
  __syncthreads();
  for (int i = threadIdx.x; i < N_CLU; i += 256) {
    int v = bins[i];
    if (v) atomicAdd(&counts[i], v);
  }
}

__global__ __launch_bounds__(1024) void mean_kernel(
    const float* __restrict__ data, const int* __restrict__ mapping,
    const int* __restrict__ counts, float* __restrict__ out) {
  __shared__ float bins[N_CLU];
  const int b = blockIdx.x;
  for (int i = threadIdx.x; i < N_CLU; i += 1024) bins[i] = 0.0f;
  __syncthreads();
  const float4* drow = reinterpret_cast<const float4*>(data + (size_t)b * N_PIX);
  const int4* map4 = reinterpret_cast<const int4*>(mapping);
  for (int i = threadIdx.x; i < N_PIX / 4; i += 1024) {
    float4 v = drow[i];
    int4 m = map4[i];
    __hip_atomic_fetch_add(&bins[m.x], v.x, __ATOMIC_RELAXED, __HIP_MEMORY_SCOPE_WORKGROUP);
    __hip_atomic_fetch_add(&bins[m.y], v.y, __ATOMIC_RELAXED, __HIP_MEMORY_SCOPE_WORKGROUP);
    __hip_atomic_fetch_add(&bins[m.z], v.z, __ATOMIC_RELAXED, __HIP_MEMORY_SCOPE_WORKGROUP);
    __hip_atomic_fetch_add(&bins[m.w], v.w, __ATOMIC_RELAXED, __HIP_MEMORY_SCOPE_WORKGROUP);
  }
  __syncthreads();
  float* orow = out + (size_t)b * N_CLU;
  for (int c = threadIdx.x; c < N_CLU; c += 1024)
    orow[c] = bins[c] / (float)counts[c];
}

// ===========================================================================
extern "C" void kernel_launch(void* const* d_in, const int* in_sizes, int n_in,
                              void* d_out, int out_size, void* d_ws, size_t ws_size,
                              hipStream_t stream) {
  const float* data = (const float*)d_in[0];   // [256][262144] fp32
  const int* mapping = (const int*)d_in[1];    // [262144] int32
  float* out = (float*)d_out;                  // [256][4096] fp32
  char* ws = (char*)d_ws;

  const size_t OFF_HIST = 0;
  const size_t OFF_BASE = (size_t)NCHUNK * N_CLU * 4;          // 4 MiB
  const size_t OFF_CNT = OFF_BASE + (size_t)N_CLU * 4;
  const size_t OFF_PERM = OFF_CNT + (size_t)N_CLU * 4;
  const size_t OFF_T = OFF_PERM + (size_t)N_PIX * 4;           // 16B-aligned
  const size_t NEED = OFF_T + (size_t)N_PIX * N_ROW * 2;       // ~133 MiB

  if (ws_size >= NEED) {
    int* hist = (int*)(ws + OFF_HIST);
    int* base = (int*)(ws + OFF_BASE);
    int* counts = (int*)(ws + OFF_CNT);
    int* perm = (int*)(ws + OFF_PERM);
    uint4* transT = (uint4*)(ws + OFF_T);

    // Transpose first (no dependency on the sort).
    const int dyn_lds = 128 * 258 * 2;  // 66048 B
    hipError_t aerr = hipFuncSetAttribute(
        (const void*)k_transpose128,
        hipFuncAttributeMaxDynamicSharedMemorySize, dyn_lds);
    if (aerr == hipSuccess) {
      k_transpose128<<<N_PIX / 128, 512, dyn_lds, stream>>>(data, transT);
    } else {
      k_transpose64<<<N_PIX / 64, 512, 0, stream>>>(data, transT);
    }

    k_hist<<<NCHUNK, 256, 0, stream>>>(mapping, hist);
    k_scan_chunks<<<N_CLU / 64, 256, 0, stream>>>(hist, counts);
    k_scan_base<<<1, 256, 0, stream>>>(counts, base);
    k_scatter<<<NCHUNK, 64, 0, stream>>>(mapping, hist, base, perm);

    k_reduce_g<<<N_CLU, 256, 0, stream>>>(transT, perm, base, counts, out);
  } else {
    int* counts = (int*)ws;
    (void)hipMemsetAsync(counts, 0, N_CLU * sizeof(int), stream);
    count_kernel<<<256, 256, 0, stream>>>(mapping, counts);
    mean_kernel<<<N_ROW, 1024, 0, stream>>>(data, mapping, counts, out);
  }
}